// Round 16
// baseline (373.873 us; speedup 1.0000x reference)
//
#include <hip/hip_runtime.h>
#include <hip/hip_bf16.h>
#include <hip/hip_fp16.h>

// GraphSAGE 3-layer + pool + linear.
// R16: agg+gemm fused into one sage_layer kernel per layer (exact fusion: a
// node's agg is consumed only by its own GEMM tile). Each block computes
// neighbor-means directly into MFMA A-fragment registers while the async
// global_load_lds B1 staging drains underneath (~22us of gather hides it);
// then pure-LDS MFMA src1, restage B2 (same 64KB), MFMA src2. Removes the
// agg16 global round-trip (25.6MB/layer) and 2 dispatch gaps per layer.
// CSR path and pool_final = R15. Numerics: fp16 A + split-fp16 W (hi+lo).

#define FH 128
#define OUTD 256
#define SCHUNK 2048

typedef unsigned int u32;
typedef unsigned short u16;
typedef __attribute__((ext_vector_type(8))) _Float16 f16frag;
typedef __attribute__((ext_vector_type(4))) float f4frag;

typedef __attribute__((address_space(3))) u32 lds_u32;
typedef __attribute__((address_space(1))) const u32 glb_u32;

__device__ inline void async_copy16(const void* g, void* l) {
    __builtin_amdgcn_global_load_lds((glb_u32*)g, (lds_u32*)l, 16, 0, 0);
}

// ==================================================== fused prep + histogram
__global__ void prep_all(const float* __restrict__ x, u16* __restrict__ x16, int n4, int PX,
                         const float* __restrict__ W0, const float* __restrict__ W1,
                         const float* __restrict__ W2, const float* __restrict__ W3,
                         const float* __restrict__ W4, const float* __restrict__ W5,
                         uint4* __restrict__ Bf, int PW,
                         const int* __restrict__ dst, int* __restrict__ cnt, int E) {
    int blk = blockIdx.x;
    if (blk < PX) {
        int id = blk * 256 + threadIdx.x;
        if (id >= n4) return;
        float4 v = *(const float4*)(x + (size_t)id * 4);
        __half h0 = __float2half(v.x), h1 = __float2half(v.y);
        __half h2 = __float2half(v.z), h3 = __float2half(v.w);
        ushort4 s;
        s.x = *(u16*)&h0; s.y = *(u16*)&h1; s.z = *(u16*)&h2; s.w = *(u16*)&h3;
        *(ushort4*)(x16 + (size_t)id * 4) = s;
    } else if (blk < PX + PW) {
        int pair = (blk - PX) * 4 + (threadIdx.x >> 6);
        if (pair >= 48) return;
        int ks = pair & 7;
        int arr = pair >> 3;
        int l = threadIdx.x & 63;
        const float* Ws[6] = {W0, W1, W2, W3, W4, W5};
        const float* W = Ws[arr];
        bool use_lo = (ks >= 4);
        int kb = (ks & 3) * 32 + (l >> 4) * 8;
        uint4* out = Bf + (size_t)arr * 4096;
        #pragma unroll
        for (int ot = 0; ot < 8; ++ot) {
            int o = ot * 16 + (l & 15);
            u32 h[8];
            #pragma unroll
            for (int i = 0; i < 8; ++i) {
                float v = W[o * 128 + kb + i];
                __half hi = __float2half(v);
                if (use_lo) {
                    float rem = v - __half2float(hi);
                    __half lo = __float2half(rem);
                    h[i] = *(u16*)&lo;
                } else {
                    h[i] = *(u16*)&hi;
                }
            }
            uint4 u;
            u.x = h[0] | (h[1] << 16);
            u.y = h[2] | (h[3] << 16);
            u.z = h[4] | (h[5] << 16);
            u.w = h[6] | (h[7] << 16);
            out[(ks * 8 + ot) * 64 + l] = u;
        }
    } else {
        int e = (blk - PX - PW) * 256 + threadIdx.x;
        if (e < E) atomicAdd(&cnt[dst[e]], 1);
    }
}

// ---------------------------------------------- scan pass A: per-block sums
__global__ void scanA_kernel(const int* __restrict__ cnt, int* __restrict__ bsum, int n) {
    __shared__ int ws[4];
    int b = blockIdx.x, t = threadIdx.x;
    int base = b * SCHUNK + t * 8;
    int s = 0;
    #pragma unroll
    for (int k = 0; k < 8; ++k) {
        int i = base + k;
        s += (i < n) ? cnt[i] : 0;
    }
    #pragma unroll
    for (int off = 32; off >= 1; off >>= 1) s += __shfl_xor(s, off, 64);
    int w = t >> 6, lane = t & 63;
    if (lane == 0) ws[w] = s;
    __syncthreads();
    if (t == 0) bsum[b] = ws[0] + ws[1] + ws[2] + ws[3];
}

// ------------ scan pass C: block offset from bsum (in-wave) + local scan
__global__ void scanC_kernel(const int* __restrict__ cnt, const int* __restrict__ bsum,
                             int NB, int* __restrict__ rp, float* __restrict__ dinv, int n) {
    __shared__ int ws[4];
    __shared__ int base_s;
    int b = blockIdx.x, t = threadIdx.x;
    if (t < 64) {
        int v = (t < NB) ? bsum[t] : 0;
        int pre = (t < b) ? v : 0;
        #pragma unroll
        for (int off = 32; off >= 1; off >>= 1) pre += __shfl_xor(pre, off, 64);
        if (t == 0) base_s = pre;
        if (b == 0) {
            int tot = v;
            #pragma unroll
            for (int off = 32; off >= 1; off >>= 1) tot += __shfl_xor(tot, off, 64);
            if (t == 0) rp[n] = tot;
        }
    }
    __syncthreads();
    int boff = base_s;
    int base = b * SCHUNK + t * 8;
    int v[8];
    int ts = 0;
    #pragma unroll
    for (int k = 0; k < 8; ++k) {
        int i = base + k;
        v[k] = (i < n) ? cnt[i] : 0;
        ts += v[k];
    }
    int w = t >> 6, lane = t & 63;
    int x = ts;
    #pragma unroll
    for (int off = 1; off < 64; off <<= 1) {
        int y = __shfl_up(x, off, 64);
        if (lane >= off) x += y;
    }
    if (lane == 63) ws[w] = x;
    __syncthreads();
    int woff = 0;
    #pragma unroll
    for (int q = 0; q < 4; ++q) woff += (q < w) ? ws[q] : 0;
    int run = boff + woff + (x - ts);
    #pragma unroll
    for (int k = 0; k < 8; ++k) {
        int i = base + k;
        if (i < n) {
            rp[i] = run;
            dinv[i] = 1.0f / (float)max(v[k], 1);
        }
        run += v[k];
    }
}

// ==================================== fused CSR scatter + graph range bounds
__global__ void scatter_bounds(const int* __restrict__ src, const int* __restrict__ dst,
                               const int* __restrict__ rp, int* __restrict__ cursor,
                               int* __restrict__ esrc, int E, int SC,
                               const int* __restrict__ batch, int* __restrict__ gstart,
                               int n, int g) {
    int blk = blockIdx.x;
    if (blk < SC) {
        int e = blk * 256 + threadIdx.x;
        if (e < E) {
            int d = dst[e];
            int pos = rp[d] + atomicAdd(&cursor[d], 1);
            esrc[pos] = src[e];
        }
    } else {
        int i = (blk - SC) * 256 + threadIdx.x;
        if (i >= n) return;
        int b = batch[i];
        int pb = (i == 0) ? -1 : batch[i - 1];
        for (int q = pb + 1; q <= b; ++q) gstart[q] = i;
        if (i == n - 1) {
            for (int q = b + 1; q <= g; ++q) gstart[q] = n;
        }
    }
}

__device__ inline void add8(float* a, uint4 u) {
    float2 f0 = __half22float2(*(__half2*)&u.x);
    float2 f1 = __half22float2(*(__half2*)&u.y);
    float2 f2 = __half22float2(*(__half2*)&u.z);
    float2 f3 = __half22float2(*(__half2*)&u.w);
    a[0] += f0.x; a[1] += f0.y; a[2] += f1.x; a[3] += f1.y;
    a[4] += f2.x; a[5] += f2.y; a[6] += f3.x; a[7] += f3.y;
}

// ================================================ fused SAGE layer (agg+GEMM)
// 256 threads (4 waves), 192-node tile, grid 261 (2 blocks/CU).
// Phase 0: issue async B1 staging (64 KB) + prefetch A2 (own-node frags).
// Phase 1: neighbor-mean aggregation straight into MFMA A-frag registers
//          (lane l: node nt*16+(l&15), feats (l>>4)*8 + s*32; fp32 accum).
//          This ~20us of gather work hides the B1 staging completely.
// Phase 2: barrier (drains staging), MFMA src1 (agg x Wl) from LDS.
// Phase 3: barrier, restage B2 into same 64 KB, barrier, MFMA src2 (h x Wr).
// Phase 4: bias (+relu), fp16 store.
__global__ __launch_bounds__(256, 2)
void sage_layer(const u16* __restrict__ h16,
                const int* __restrict__ rp, const int* __restrict__ esrc,
                const float* __restrict__ dinv,
                const uint4* __restrict__ Bf1, const uint4* __restrict__ Bf2,
                const float* __restrict__ bias, u16* __restrict__ out16,
                int n_nodes, int do_relu) {
    __shared__ uint4 Bl[4096];  // 64 KB, holds B1 then B2
    int tid = threadIdx.x;
    int l = tid & 63;
    int wv = tid >> 6;
    int bn0 = blockIdx.x * 192 + wv * 48;
    int m = l & 15, q = l >> 4;  // q in 0..3
    int qb = q * 8;

    // ---- phase 0: async B1 staging + A2 prefetch ----
    #pragma unroll
    for (int u = 0; u < 16; ++u)
        async_copy16(Bf1 + (size_t)u * 256 + wv * 64 + l,
                     &Bl[u * 256 + wv * 64]);
    f16frag Af2[3][4];
    #pragma unroll
    for (int nt = 0; nt < 3; ++nt)
        #pragma unroll
        for (int s = 0; s < 4; ++s)
            Af2[nt][s] = *(const f16frag*)(h16 + (size_t)(bn0 + nt * 16 + m) * FH + s * 32 + qb);

    // ---- phase 1: aggregation into A-frag registers ----
    f16frag Af1[3][4];
    #pragma unroll
    for (int nt = 0; nt < 3; ++nt) {
        int node = bn0 + nt * 16 + m;
        float a[4][8];
        #pragma unroll
        for (int s = 0; s < 4; ++s)
            #pragma unroll
            for (int i = 0; i < 8; ++i) a[s][i] = 0.f;
        int s0 = 0, s1 = 0;
        if (node < n_nodes) { s0 = rp[node]; s1 = rp[node + 1]; }
        int j = s0;
        for (; j + 2 <= s1; j += 2) {
            int i0 = esrc[j], i1 = esrc[j + 1];
            const u16* p0 = h16 + (size_t)i0 * FH + qb;
            const u16* p1 = h16 + (size_t)i1 * FH + qb;
            uint4 u0[4], u1[4];
            #pragma unroll
            for (int s = 0; s < 4; ++s) {
                u0[s] = *(const uint4*)(p0 + s * 32);
                u1[s] = *(const uint4*)(p1 + s * 32);
            }
            #pragma unroll
            for (int s = 0; s < 4; ++s) { add8(a[s], u0[s]); add8(a[s], u1[s]); }
        }
        if (j < s1) {
            const u16* p0 = h16 + (size_t)esrc[j] * FH + qb;
            #pragma unroll
            for (int s = 0; s < 4; ++s) {
                uint4 u0 = *(const uint4*)(p0 + s * 32);
                add8(a[s], u0);
            }
        }
        float di = (node < n_nodes) ? dinv[node] : 0.f;
        #pragma unroll
        for (int s = 0; s < 4; ++s) {
            u32 oh[4];
            #pragma unroll
            for (int i = 0; i < 4; ++i) {
                __half h0 = __float2half(a[s][2 * i] * di);
                __half h1 = __float2half(a[s][2 * i + 1] * di);
                oh[i] = (u32)(*(u16*)&h0) | ((u32)(*(u16*)&h1) << 16);
            }
            uint4 u; u.x = oh[0]; u.y = oh[1]; u.z = oh[2]; u.w = oh[3];
            Af1[nt][s] = *(f16frag*)&u;
        }
    }

    f4frag acc[3][8];
    #pragma unroll
    for (int i = 0; i < 3; ++i)
        #pragma unroll
        for (int o = 0; o < 8; ++o)
            acc[i][o] = (f4frag){0.f, 0.f, 0.f, 0.f};

    __syncthreads();   // drains B1 staging (and all loads)

    // ---- phase 2: MFMA src1 (agg x Wl) ----
    #pragma unroll
    for (int s = 0; s < 4; ++s) {
        {
            f16frag B[8];
            #pragma unroll
            for (int ot = 0; ot < 8; ++ot)
                B[ot] = *(const f16frag*)&Bl[(size_t)(s * 8 + ot) * 64 + l];
            #pragma unroll
            for (int ot = 0; ot < 8; ++ot)
                #pragma unroll
                for (int nt = 0; nt < 3; ++nt)
                    acc[nt][ot] = __builtin_amdgcn_mfma_f32_16x16x32_f16(Af1[nt][s], B[ot], acc[nt][ot], 0, 0, 0);
        }
        {
            f16frag B[8];
            #pragma unroll
            for (int ot = 0; ot < 8; ++ot)
                B[ot] = *(const f16frag*)&Bl[(size_t)((s + 4) * 8 + ot) * 64 + l];
            #pragma unroll
            for (int ot = 0; ot < 8; ++ot)
                #pragma unroll
                for (int nt = 0; nt < 3; ++nt)
                    acc[nt][ot] = __builtin_amdgcn_mfma_f32_16x16x32_f16(Af1[nt][s], B[ot], acc[nt][ot], 0, 0, 0);
        }
    }

    // ---- phase 3: restage B2, MFMA src2 (h x Wr) ----
    __syncthreads();   // all waves done reading B1
    #pragma unroll
    for (int u = 0; u < 16; ++u)
        async_copy16(Bf2 + (size_t)u * 256 + wv * 64 + l,
                     &Bl[u * 256 + wv * 64]);
    __syncthreads();   // staging complete

    #pragma unroll
    for (int s = 0; s < 4; ++s) {
        {
            f16frag B[8];
            #pragma unroll
            for (int ot = 0; ot < 8; ++ot)
                B[ot] = *(const f16frag*)&Bl[(size_t)(s * 8 + ot) * 64 + l];
            #pragma unroll
            for (int ot = 0; ot < 8; ++ot)
                #pragma unroll
                for (int nt = 0; nt < 3; ++nt)
                    acc[nt][ot] = __builtin_amdgcn_mfma_f32_16x16x32_f16(Af2[nt][s], B[ot], acc[nt][ot], 0, 0, 0);
        }
        {
            f16frag B[8];
            #pragma unroll
            for (int ot = 0; ot < 8; ++ot)
                B[ot] = *(const f16frag*)&Bl[(size_t)((s + 4) * 8 + ot) * 64 + l];
            #pragma unroll
            for (int ot = 0; ot < 8; ++ot)
                #pragma unroll
                for (int nt = 0; nt < 3; ++nt)
                    acc[nt][ot] = __builtin_amdgcn_mfma_f32_16x16x32_f16(Af2[nt][s], B[ot], acc[nt][ot], 0, 0, 0);
        }
    }

    // ---- phase 4: epilogue (D: col=l&15, row=q*4+r) ----
    #pragma unroll
    for (int nt = 0; nt < 3; ++nt)
        #pragma unroll
        for (int r = 0; r < 4; ++r) {
            int node = bn0 + nt * 16 + q * 4 + r;
            #pragma unroll
            for (int ot = 0; ot < 8; ++ot) {
                float v = acc[nt][ot][r] + bias[ot * 16 + m];
                if (do_relu) v = fmaxf(v, 0.f);
                __half hv = __float2half(v);
                out16[(size_t)node * FH + ot * 16 + m] = *(u16*)&hv;
            }
        }
}

// --------------------------------------------- fused pooling + final linear
__global__ __launch_bounds__(256, 2)
void pool_final(const u16* __restrict__ h16, const int* __restrict__ gstart,
                const float* __restrict__ Wlin, const float* __restrict__ blin,
                float* __restrict__ out) {
    __shared__ float smax[16][FH];
    __shared__ float ssum[16][FH];
    __shared__ float pr[2 * FH];
    int g = blockIdx.x;
    int tid = threadIdx.x;
    int way = tid >> 4;
    int lane = tid & 15;
    int f = lane * 8;
    int s = gstart[g], e = gstart[g + 1];

    float mx[8], sm[8];
    #pragma unroll
    for (int i = 0; i < 8; ++i) { mx[i] = -INFINITY; sm[i] = 0.f; }
    for (int n = s + way; n < e; n += 16) {
        uint4 u = *(const uint4*)(h16 + (size_t)n * FH + f);
        float2 f0 = __half22float2(*(__half2*)&u.x);
        float2 f1 = __half22float2(*(__half2*)&u.y);
        float2 f2 = __half22float2(*(__half2*)&u.z);
        float2 f3 = __half22float2(*(__half2*)&u.w);
        float v[8] = {f0.x, f0.y, f1.x, f1.y, f2.x, f2.y, f3.x, f3.y};
        #pragma unroll
        for (int i = 0; i < 8; ++i) {
            mx[i] = fmaxf(mx[i], v[i]);
            sm[i] += v[i];
        }
    }
    #pragma unroll
    for (int i = 0; i < 8; ++i) {
        smax[way][f + i] = mx[i];
        ssum[way][f + i] = sm[i];
    }
    __syncthreads();
    int c = e - s;
    if (tid < FH) {
        float m2 = -INFINITY, s2 = 0.f;
        #pragma unroll
        for (int w2 = 0; w2 < 16; ++w2) {
            m2 = fmaxf(m2, smax[w2][tid]);
            s2 += ssum[w2][tid];
        }
        pr[tid] = (c > 0) ? m2 : 0.f;
        pr[FH + tid] = s2 / (float)max(c, 1);
    }
    __syncthreads();
    int o = tid;
    const float4* wr = (const float4*)(Wlin + (size_t)o * (2 * FH));
    float acc = 0.f;
    #pragma unroll
    for (int j = 0; j < (2 * FH) / 4; ++j) {
        float4 wv = wr[j];
        acc += wv.x * pr[j * 4 + 0] + wv.y * pr[j * 4 + 1] +
               wv.z * pr[j * 4 + 2] + wv.w * pr[j * 4 + 3];
    }
    out[(size_t)g * OUTD + o] = acc + blin[o];
}

extern "C" void kernel_launch(void* const* d_in, const int* in_sizes, int n_in,
                              void* d_out, int out_size, void* d_ws, size_t ws_size,
                              hipStream_t stream) {
    const float* x     = (const float*)d_in[0];
    const int*   ei    = (const int*)d_in[1];
    const int*   batch = (const int*)d_in[2];
    const float* W1l = (const float*)d_in[3];
    const float* b1  = (const float*)d_in[4];
    const float* W1r = (const float*)d_in[5];
    const float* W2l = (const float*)d_in[6];
    const float* b2  = (const float*)d_in[7];
    const float* W2r = (const float*)d_in[8];
    const float* W3l = (const float*)d_in[9];
    const float* b3  = (const float*)d_in[10];
    const float* W3r = (const float*)d_in[11];
    const float* Wlin = (const float*)d_in[12];
    const float* blin = (const float*)d_in[13];
    float* out = (float*)d_out;

    const int E = in_sizes[1] / 2;
    const int N = in_sizes[2];
    const int G = out_size / OUTD;
    const int* src = ei;
    const int* dst = ei + E;
    const int NB = (N + SCHUNK - 1) / SCHUNK;
    const int GB = (N + 191) / 192;
    const int NP = GB * 192;

    // ---- workspace carve-up ----
    char* w = (char*)d_ws;
    auto alloc = [&](size_t bytes) {
        void* p = (void*)w;
        w += (bytes + 255) & ~(size_t)255;
        return p;
    };
    int*   cnt    = (int*)alloc((size_t)2 * N * sizeof(int));
    int*   cursor = cnt + N;
    int*   rp     = (int*)alloc((size_t)(N + 1) * sizeof(int));
    int*   esrc   = (int*)alloc((size_t)E * sizeof(int));
    int*   gstart = (int*)alloc((size_t)(G + 1) * sizeof(int));
    float* dinv   = (float*)alloc((size_t)N * sizeof(float));
    int*   bsum   = (int*)alloc(64 * sizeof(int));
    u16*   x16    = (u16*)alloc((size_t)NP * FH * sizeof(u16));
    u16*   hA16   = (u16*)alloc((size_t)NP * FH * sizeof(u16));
    u16*   hB16   = (u16*)alloc((size_t)NP * FH * sizeof(u16));
    uint4* BF     = (uint4*)alloc((size_t)6 * 4096 * sizeof(uint4));
    (void)ws_size;

    // ---- fused prep (prep_x | prep_w | hist) ----
    hipMemsetAsync(cnt, 0, (size_t)2 * N * sizeof(int), stream);
    const int n4 = N * 32;
    const int PX = (n4 + 255) / 256;
    const int PW = 12;
    const int PH = (E + 255) / 256;
    prep_all<<<PX + PW + PH, 256, 0, stream>>>(x, x16, n4, PX,
                                               W1l, W1r, W2l, W2r, W3l, W3r, BF, PW,
                                               dst, cnt, E);

    // ---- CSR build ----
    scanA_kernel<<<NB, 256, 0, stream>>>(cnt, bsum, N);
    scanC_kernel<<<NB, 256, 0, stream>>>(cnt, bsum, NB, rp, dinv, N);
    const int SC = (E + 255) / 256;
    const int GBND = (N + 255) / 256;
    scatter_bounds<<<SC + GBND, 256, 0, stream>>>(src, dst, rp, cursor, esrc, E, SC,
                                                  batch, gstart, N, G);

    // ---- fused layers (agg + GEMM in one dispatch each) ----
    sage_layer<<<GB, 256, 0, stream>>>(x16, rp, esrc, dinv,
                                       BF + 0 * 4096, BF + 1 * 4096, b1, hA16, N, 1);
    sage_layer<<<GB, 256, 0, stream>>>(hA16, rp, esrc, dinv,
                                       BF + 2 * 4096, BF + 3 * 4096, b2, hB16, N, 1);
    sage_layer<<<GB, 256, 0, stream>>>(hB16, rp, esrc, dinv,
                                       BF + 4 * 4096, BF + 5 * 4096, b3, hA16, N, 0);

    // ---- fused pool + head ----
    pool_final<<<G, 256, 0, stream>>>(hA16, gstart, Wlin, blin, out);
}